// Round 7
// baseline (292.212 us; speedup 1.0000x reference)
//
#include <hip/hip_runtime.h>
#include <stdint.h>
#include <stddef.h>

// Problem geometry (B=4, S=2048, DIN=4096, DOUT=4096)
constexpr int MDIM = 8192;   // B*S
constexpr int NDIM = 4096;   // DOUT
constexpr int KDIM = 4096;   // DIN

using f32x4 = __attribute__((ext_vector_type(4))) float;
using s16x4 = __attribute__((ext_vector_type(4))) short;
using s16x8 = __attribute__((ext_vector_type(8))) short;
using i32x4 = __attribute__((ext_vector_type(4))) int;

__device__ __forceinline__ short f32_to_bf16_rn(float f) {
  union { float f; uint32_t u; } v; v.f = f;
  uint32_t r = (v.u + 0x7FFFu + ((v.u >> 16) & 1u)) >> 16;  // RTN-even
  return (short)(uint16_t)r;
}

// ---------------- prepass: f32 -> bf16 ----------------
__global__ void __launch_bounds__(256) cvt_x_kernel(const float* __restrict__ in,
                                                    short* __restrict__ out, int n8) {
  int i = blockIdx.x * 256 + threadIdx.x;
  const int stride = gridDim.x * 256;
  for (; i < n8; i += stride) {
    const f32x4* p = (const f32x4*)(in + (size_t)i * 8);
    f32x4 a = p[0];
    f32x4 b = p[1];
    s16x8 o;
#pragma unroll
    for (int j = 0; j < 4; ++j) { o[j] = f32_to_bf16_rn(a[j]); o[j + 4] = f32_to_bf16_rn(b[j]); }
    *(s16x8*)(out + (size_t)i * 8) = o;
  }
}

// ---------------- prepass: int32 (quantized weight) -> bf16 (exact) ----------------
__global__ void __launch_bounds__(256) cvt_w_kernel(const int* __restrict__ in,
                                                    short* __restrict__ out, int n8) {
  int i = blockIdx.x * 256 + threadIdx.x;
  const int stride = gridDim.x * 256;
  for (; i < n8; i += stride) {
    const i32x4* p = (const i32x4*)(in + (size_t)i * 8);
    i32x4 a = p[0];
    i32x4 b = p[1];
    s16x8 o;
#pragma unroll
    for (int j = 0; j < 4; ++j) {
      o[j]     = f32_to_bf16_rn((float)a[j]);
      o[j + 4] = f32_to_bf16_rn((float)b[j]);
    }
    *(s16x8*)(out + (size_t)i * 8) = o;
  }
}

// =====================================================================
// 256x256 GEMM, 4-region pipeline, BALANCED reads (6/region) and
// 2 barriers per K-tile (end-R2, end-R4 only), vmcnt(4) counted waits.
//   A [M][K] bf16, Bw [N][K] bf16 (= B^T), C = A*Bw^T * scale + bias
// LDS per matrix per buffer (32 KiB): subtiled [ks][st_r][16][64B],
// XOR swizzle phys = lin ^ (((lin>>9)&1)<<5)  (st_16x32).
//
// Per tile t (cur=t&1, nxt=(t+1)&1), frag sets E=0 / O=1:
//  R1: rd afO=A4-7(cur,ks0), bfO(j01)=B01(cur,ks1); stage B-ks1(t+1);
//      MFMA acc[0-3] (afE x bfE)
//  R2: rd afE=A0-3(cur,ks1), bfO(j23)=B23(cur,ks1); stage A-ks1(t+1);
//      MFMA acc[4-7] (afO x bfE); vmcnt(4); BAR
//  R3: rd afO=A4-7(cur,ks1), bfE(j01)=B01(nxt,ks0); stage B-ks0(t+2);
//      MFMA acc[0-3] (afE x bfO)
//  R4: rd afE=A0-3(nxt,ks0), bfE(j23)=B23(nxt,ks0); stage A-ks0(t+2);
//      MFMA acc[4-7] (afO x bfO); vmcnt(4); BAR
// Ledger (per wave): end-R2(t) outstanding = {R3(t-1),R4(t-1),R1(t),R2(t)}=8
//   -> vmcnt(4) completes R3/R4(t-1) = t+1-ks0 (needed by R3/R4(t) reads).
// end-R4(t) outstanding = {R1..R4(t)}=8 -> vmcnt(4) completes R1/R2(t) =
//   t+1-ks1 (needed by R1/R2(t+1) reads). Prologue stages t0(all)+t1-ks0 so
//   the first end-R2 wait matches the invariant. WAR: each staged region's
//   last reader finished (lgkm before its consuming MFMA) >=1 barrier before
//   the overwriting stage (verified for all 4 slots).
// Tail: t62 {s3,s4 off; vm4=0 since only 4 outstanding}, t63 all off.
// =====================================================================

#define BAR asm volatile("s_barrier" ::: "memory")
#define WAITVM(n) asm volatile("s_waitcnt vmcnt(" #n ")" ::: "memory")

#define GLL(src, dst) __builtin_amdgcn_global_load_lds(                     \
    (const __attribute__((address_space(1))) void*)(src),                   \
    (__attribute__((address_space(3))) void*)(dst), 16, 0, 0)

// grow: const char* global row base; ldsmat: 0 (A) or 65536 (B)
#define STAGE(grow, ldsmat, ks, tau) do {                                   \
  const int buf_ = (tau) & 1;                                               \
  GLL((grow) + (size_t)r0 * 8192 + (size_t)(tau) * 128 + (ks) * 64 + cb,    \
      lds + (ldsmat) + buf_ * 32768 + (ks) * 16384 + t * 16);               \
  GLL((grow) + (size_t)r1 * 8192 + (size_t)(tau) * 128 + (ks) * 64 + cb,    \
      lds + (ldsmat) + buf_ * 32768 + (ks) * 16384 + 8192 + t * 16);        \
} while (0)

#define LDA(bufc, ks, i) (*(const s16x8*)(lds + (bufc) * 32768 + (ks) * 16384 \
    + (wm * 8 + (i)) * 1024 + laneoff))
#define LDB(bufc, ks, j) (*(const s16x8*)(lds + 65536 + (bufc) * 32768        \
    + (ks) * 16384 + (wn * 4 + (j)) * 1024 + laneoff))

#define READ_A4(set, bufc, ks, base) do {                                   \
  _Pragma("unroll") for (int i_ = 0; i_ < 4; ++i_)                          \
    af[set][i_] = LDA(bufc, ks, (base) + i_);                               \
} while (0)
#define READ_B2(set, bufc, ks, jbase) do {                                  \
  bf[set][(jbase)]     = LDB(bufc, ks, (jbase));                            \
  bf[set][(jbase) + 1] = LDB(bufc, ks, (jbase) + 1);                        \
} while (0)

#define MFMA16(accbase, aset, bset) do {                                    \
  __builtin_amdgcn_s_setprio(1);                                            \
  _Pragma("unroll") for (int i_ = 0; i_ < 4; ++i_)                          \
  _Pragma("unroll") for (int j_ = 0; j_ < 4; ++j_)                          \
    acc[(accbase) + i_][j_] = __builtin_amdgcn_mfma_f32_16x16x32_bf16(      \
        af[aset][i_], bf[bset][j_], acc[(accbase) + i_][j_], 0, 0, 0);      \
  __builtin_amdgcn_s_setprio(0);                                            \
} while (0)

// vmN: 4 -> vmcnt(4), 0 -> vmcnt(0), -1 -> none.
#define KTILE(t_, cur, nxt, s1, s2, s3, s4, vm2, vm4, r3x, r4x) do {        \
  /* R1 */                                                                  \
  READ_A4(1, cur, 0, 4); READ_B2(1, cur, 1, 0);                             \
  if (s1) STAGE(Brow, 65536, 1, (t_) + 1);                                  \
  MFMA16(0, 0, 0);                                                          \
  /* R2 */                                                                  \
  READ_A4(0, cur, 1, 0); READ_B2(1, cur, 1, 2);                             \
  if (s2) STAGE(Arow, 0, 1, (t_) + 1);                                      \
  MFMA16(4, 1, 0);                                                          \
  if ((vm2) == 4) { WAITVM(4); } else if ((vm2) == 0) { WAITVM(0); }        \
  BAR;                                                                      \
  /* R3 */                                                                  \
  READ_A4(1, cur, 1, 4);                                                    \
  if (r3x) READ_B2(0, nxt, 0, 0);                                           \
  if (s3) STAGE(Brow, 65536, 0, (t_) + 2);                                  \
  MFMA16(0, 0, 1);                                                          \
  /* R4 */                                                                  \
  if (r4x) { READ_A4(0, nxt, 0, 0); READ_B2(0, nxt, 0, 2); }                \
  if (s4) STAGE(Arow, 0, 0, (t_) + 2);                                      \
  MFMA16(4, 1, 1);                                                          \
  if ((vm4) == 4) { WAITVM(4); } else if ((vm4) == 0) { WAITVM(0); }        \
  BAR;                                                                      \
} while (0)

__global__ void __launch_bounds__(512, 2) gemm_bf16_pipe(
    const short* __restrict__ A, const short* __restrict__ Bw,
    const float* __restrict__ scale_p, const float* __restrict__ bias,
    float* __restrict__ out) {
  __shared__ __align__(16) char lds[131072];

  const int t      = threadIdx.x;        // 0..511
  const int lane   = t & 63;
  const int wave   = t >> 6;
  const int wm     = wave >> 2;          // 0..1  (row half: 128 rows)
  const int wn     = wave & 3;           // 0..3  (col quarter: 64 cols)
  const int lane15 = lane & 15;
  const int lh     = lane >> 4;          // 0..3

  // swizzled read offset (round-3 verified, zero bank conflicts).
  // XOR, not '+': lh*16 occupies bit 5.
  const int laneoff = (lane15 * 64 + lh * 16) ^ ((lane15 & 8) << 2);

  // stage decode: LDS slot o = l*8192 + t*16 holds element a = o ^ (((o>>9)&1)<<5)
  const int ax = ((t >> 5) & 1) << 5;
  const int a0 = (t * 16) ^ ax;
  const int a1 = (8192 + t * 16) ^ ax;
  const int r0 = (((a0 >> 10) & 15) << 4) | ((a0 >> 6) & 15);
  const int r1 = (((a1 >> 10) & 15) << 4) | ((a1 >> 6) & 15);
  const int cb = a0 & 63;

  // XCD-aware swizzle: nwg = 512 (divisible by 8)
  const int bid   = blockIdx.x;
  const int wg    = (bid & 7) * 64 + (bid >> 3);
  const int ntile = wg & 15;             // 16 n-tiles
  const int mtile = wg >> 4;             // 32 m-tiles
  const int m0 = mtile * 256;
  const int n0 = ntile * 256;

  const char* Arow = (const char*)(A + (size_t)m0 * KDIM);
  const char* Brow = (const char*)(Bw + (size_t)n0 * KDIM);

  f32x4 acc[8][4] = {};
  s16x8 af[2][4], bf[2][4];

  // Prologue: t0 q0-q3 + t1 {B-ks0, A-ks0} = 6 stages (12 loads/wave-slice).
  STAGE(Brow, 65536, 0, 0);   // t0 q0: B ks0
  STAGE(Arow, 0,     0, 0);   // t0 q1: A ks0
  STAGE(Brow, 65536, 1, 0);   // t0 q2: B ks1
  STAGE(Arow, 0,     1, 0);   // t0 q3: A ks1
  STAGE(Brow, 65536, 0, 1);   // t1 B ks0  (plays R3(t-1) role)
  STAGE(Arow, 0,     0, 1);   // t1 A ks0  (plays R4(t-1) role)
  WAITVM(4);                  // t0 fully landed; t1-ks0 (4 loads) in flight
  BAR;
  // pre-read frags for R1(t0): afE = A0-3(t0,ks0), bfE = B0-3(t0,ks0)
  READ_A4(0, 0, 0, 0);
  READ_B2(0, 0, 0, 0);
  READ_B2(0, 0, 0, 2);

  // Main: tiles 0..61 in pairs (buf index compile-time), then 62, 63.
#pragma unroll 1
  for (int tp = 0; tp < 31; ++tp) {
    const int t2 = tp * 2;
    KTILE(t2,     0, 1, 1, 1, 1, 1, 4, 4, 1, 1);
    KTILE(t2 + 1, 1, 0, 1, 1, 1, 1, 4, 4, 1, 1);
  }
  // t62: stage only t63-ks1 (R1,R2); vm4=0 (only 4 outstanding = t63-ks1,
  // needed by R1/R2(63) reads). R3/R4 still read t63-ks0 (landed via vm2).
  KTILE(62, 0, 1, 1, 1, 0, 0, 4, 0, 1, 1);
  // t63: no stages, no next-tile reads, no waits needed.
  KTILE(63, 1, 0, 0, 0, 0, 0, -1, -1, 0, 0);

  // Epilogue: D layout col=lane&15, row=(lane>>4)*4+q (m89-verified)
  const float s = scale_p[0];
#pragma unroll
  for (int j = 0; j < 4; ++j) {
    const int col = n0 + wn * 64 + j * 16 + lane15;
    const float bv = bias[col];
#pragma unroll
    for (int i = 0; i < 8; ++i) {
      const int row = m0 + wm * 128 + i * 16 + lh * 4;
#pragma unroll
      for (int q = 0; q < 4; ++q)
        out[(size_t)(row + q) * NDIM + col] = acc[i][j][q] * s + bv;
    }
  }
}

// ---------------- fallback: m97-style reg-staging with on-the-fly conversion ----------------
constexpr int FTILE = 128;
constexpr int FBK   = 64;

__global__ void __launch_bounds__(256) gemm_raw(
    const float* __restrict__ X, const int* __restrict__ W,
    const float* __restrict__ scale_p, const float* __restrict__ bias,
    float* __restrict__ out) {
  __shared__ short As[FTILE * FBK];
  __shared__ short Bs[FTILE * FBK];

  const int t      = threadIdx.x;
  const int lane   = t & 63;
  const int wave   = t >> 6;
  const int wm     = wave >> 1;
  const int wn     = wave & 1;
  const int lane15   = lane & 15;
  const int laneHalf = lane >> 4;

  const int bid   = blockIdx.x;
  const int wg    = (bid & 7) * 256 + (bid >> 3);
  const int ntile = wg & 31;
  const int mtile = wg >> 5;
  const int m0 = mtile * FTILE;
  const int n0 = ntile * FTILE;

  f32x4 acc[4][4] = {};

  for (int k0 = 0; k0 < KDIM; k0 += FBK) {
    __syncthreads();
#pragma unroll
    for (int r = 0; r < 8; ++r) {
      const int f   = r * 256 + t;
      const int row = f >> 4;
      const int c4  = (f & 15) * 4;
      f32x4 v = *(const f32x4*)(X + (size_t)(m0 + row) * KDIM + (k0 + c4));
      s16x4 h;
#pragma unroll
      for (int j = 0; j < 4; ++j) h[j] = f32_to_bf16_rn(v[j]);
      *(s16x4*)&As[row * FBK + c4] = h;

      i32x4 wv = *(const i32x4*)(W + (size_t)(n0 + row) * KDIM + (k0 + c4));
      s16x4 hw;
#pragma unroll
      for (int j = 0; j < 4; ++j) hw[j] = f32_to_bf16_rn((float)wv[j]);
      *(s16x4*)&Bs[row * FBK + c4] = hw;
    }
    __syncthreads();

#pragma unroll
    for (int kk = 0; kk < FBK; kk += 32) {
      const int kb = kk + laneHalf * 8;
      s16x8 af[4], bf[4];
#pragma unroll
      for (int i = 0; i < 4; ++i) {
        af[i] = *(const s16x8*)&As[(wm * 64 + i * 16 + lane15) * FBK + kb];
        bf[i] = *(const s16x8*)&Bs[(wn * 64 + i * 16 + lane15) * FBK + kb];
      }
#pragma unroll
      for (int i = 0; i < 4; ++i)
#pragma unroll
        for (int j = 0; j < 4; ++j)
          acc[i][j] = __builtin_amdgcn_mfma_f32_16x16x32_bf16(af[i], bf[j], acc[i][j], 0, 0, 0);
    }
  }

  const float s = scale_p[0];
#pragma unroll
  for (int j = 0; j < 4; ++j) {
    const int col = n0 + wn * 64 + j * 16 + lane15;
    const float bv = bias[col];
#pragma unroll
    for (int i = 0; i < 4; ++i) {
      const int row = m0 + wm * 64 + i * 16 + laneHalf * 4;
#pragma unroll
      for (int q = 0; q < 4; ++q)
        out[(size_t)(row + q) * NDIM + col] = acc[i][j][q] * s + bv;
    }
  }
}

extern "C" void kernel_launch(void* const* d_in, const int* in_sizes, int n_in,
                              void* d_out, int out_size, void* d_ws, size_t ws_size,
                              hipStream_t stream) {
  const float* x     = (const float*)d_in[0];
  const int*   w     = (const int*)d_in[1];    // integer inputs materialize as int32
  const float* scale = (const float*)d_in[2];
  const float* bias  = (const float*)d_in[3];
  float* out = (float*)d_out;

  const size_t a_elems = (size_t)MDIM * KDIM;  // 33,554,432
  const size_t b_elems = (size_t)NDIM * KDIM;  // 16,777,216
  const size_t need    = (a_elems + b_elems) * sizeof(short);  // 100,663,296 B

  if (ws_size >= need) {
    short* Abf = (short*)d_ws;
    short* Wbf = Abf + a_elems;
    cvt_x_kernel<<<2048, 256, 0, stream>>>(x, Abf, (int)(a_elems / 8));
    cvt_w_kernel<<<2048, 256, 0, stream>>>(w, Wbf, (int)(b_elems / 8));
    const int nwg = (MDIM / 256) * (NDIM / 256);  // 32*16 = 512
    gemm_bf16_pipe<<<nwg, 512, 0, stream>>>(Abf, Wbf, scale, bias, out);
  } else {
    const int nwg = (MDIM / FTILE) * (NDIM / FTILE);  // 2048
    gemm_raw<<<nwg, 256, 0, stream>>>(x, w, scale, bias, out);
  }
}

// Round 8
// 184.444 us; speedup vs baseline: 1.5843x; 1.5843x over previous
//
#include <hip/hip_runtime.h>
#include <stdint.h>
#include <stddef.h>

// Problem geometry (B=4, S=2048, DIN=4096, DOUT=4096)
constexpr int MDIM = 8192;   // B*S
constexpr int NDIM = 4096;   // DOUT
constexpr int KDIM = 4096;   // DIN

using f32x4 = __attribute__((ext_vector_type(4))) float;
using s16x4 = __attribute__((ext_vector_type(4))) short;
using s16x8 = __attribute__((ext_vector_type(8))) short;
using i32x4 = __attribute__((ext_vector_type(4))) int;

__device__ __forceinline__ short f32_to_bf16_rn(float f) {
  union { float f; uint32_t u; } v; v.f = f;
  uint32_t r = (v.u + 0x7FFFu + ((v.u >> 16) & 1u)) >> 16;  // RTN-even
  return (short)(uint16_t)r;
}

// ---------------- prepass 1: x f32 -> i8, per-row symmetric scale ----------------
// One block per row (8192 rows x 4096 elems). sx[row] = rowmax/127.
__global__ void __launch_bounds__(256) quant_x_kernel(const float* __restrict__ in,
                                                      signed char* __restrict__ out,
                                                      float* __restrict__ sx) {
  const int row = blockIdx.x;
  const int t   = threadIdx.x;
  const float* rp = in + (size_t)row * KDIM;
  f32x4 v[4];
  float m = 0.0f;
#pragma unroll
  for (int j = 0; j < 4; ++j) {
    v[j] = *(const f32x4*)(rp + t * 16 + j * 4);
#pragma unroll
    for (int e = 0; e < 4; ++e) m = fmaxf(m, __builtin_fabsf(v[j][e]));
  }
#pragma unroll
  for (int off = 32; off > 0; off >>= 1) m = fmaxf(m, __shfl_xor(m, off, 64));
  __shared__ float wmax[4];
  const int wv = t >> 6, ln = t & 63;
  if (ln == 0) wmax[wv] = m;
  __syncthreads();
  m = fmaxf(fmaxf(wmax[0], wmax[1]), fmaxf(wmax[2], wmax[3]));
  const float inv = (m > 0.0f) ? (127.0f / m) : 0.0f;
  if (t == 0) sx[row] = m * (1.0f / 127.0f);
  i32x4 o;
#pragma unroll
  for (int j = 0; j < 4; ++j) {
    int b[4];
#pragma unroll
    for (int e = 0; e < 4; ++e) {
      int q = (int)rintf(v[j][e] * inv);
      q = q < -127 ? -127 : (q > 127 ? 127 : q);
      b[e] = q & 255;
    }
    o[j] = b[0] | (b[1] << 8) | (b[2] << 16) | (b[3] << 24);
  }
  *(i32x4*)(out + (size_t)row * KDIM + t * 16) = o;
}

// ---------------- prepass 2: weight int32 -> i8 (exact, low-byte pack) ----------------
__global__ void __launch_bounds__(256) quant_w_kernel(const int* __restrict__ in,
                                                      signed char* __restrict__ out, int n16) {
  int i = blockIdx.x * 256 + threadIdx.x;
  const int stride = gridDim.x * 256;
  for (; i < n16; i += stride) {
    const i32x4* p = (const i32x4*)(in + (size_t)i * 16);
    i32x4 o;
#pragma unroll
    for (int j = 0; j < 4; ++j) {
      i32x4 a = p[j];
      o[j] = (a[0] & 255) | ((a[1] & 255) << 8) | ((a[2] & 255) << 16) | ((a[3] & 255) << 24);
    }
    *(i32x4*)(out + (size_t)i * 16) = o;
  }
}

// =====================================================================
// 256x256 i8 GEMM, 2-region pipeline, mfma_i32_16x16x64_i8 (K-tile = 64).
//   A [M][K] i8 (per-row scaled x), Bw [N][K] i8 (exact weight)
//   out = (i32 acc) * sx[row] * s_w + bias[col]
// LDS 64 KiB: A at 0, B at 32768; per matrix per buffer 16 KiB =
// [256 rows][64 B], XOR swizzle phys = lin ^ (((lin>>9)&1)<<5) — identical
// geometry to the round-3 ZERO-CONFLICT pattern (16-row frags, 16B cols).
// Frag (16x16x64 i8): lane holds row=lane&15, k=(lane>>4)*16+e (1 b128).
//
// Per tile t (cur=t&1, nxt=!cur):
//  R1: rd afhi=A4-7(cur) [4], bfr[nxt]=B(t+1) [4]; stage B(t+2)->cur;
//      MFMA acc[0-3](aflo, bfr[cur]); vmcnt(2); BAR
//  R2: rd aflo=A0-3(t+1)(nxt) [4]; stage A(t+2)->cur;
//      MFMA acc[4-7](afhi, bfr[cur]); vmcnt(2); BAR
// Ledger: start-R1(t) outstanding {A(t+1)}=2. R1 issues B(t+2) -> 4;
//   vmcnt(2) retires A(t+1) (read by R2(t)). R2 issues A(t+2) -> 4;
//   vmcnt(2) retires B(t+2) (read by R1(t+1)). B(t+1) was retired at
//   end-R2(t-1). Prologue {B0,A0,B1,A1}+vmcnt(2) matches the invariant.
// WAR: stage into cur overwrites data whose last ds_read was >=1 barrier
//   earlier + HBM latency later — safe (same discipline as rounds 3-7).
// Tail: t62 {s off, vm1=0 (only A(63) outstanding)}, t63 {no reads/stages}.
// =====================================================================

#define BAR asm volatile("s_barrier" ::: "memory")
#define WAITVM(n) asm volatile("s_waitcnt vmcnt(" #n ")" ::: "memory")

#define GLL(src, dst) __builtin_amdgcn_global_load_lds(                     \
    (const __attribute__((address_space(1))) void*)(src),                   \
    (__attribute__((address_space(3))) void*)(dst), 16, 0, 0)

// grow: const char* global row base, row stride 4096 B (i8)
#define STG(grow, ldsmat, tau) do {                                         \
  const int buf_ = (tau) & 1;                                               \
  GLL((grow) + (size_t)r0 * 4096 + (size_t)(tau) * 64 + cb,                 \
      lds + (ldsmat) + buf_ * 16384 + t * 16);                              \
  GLL((grow) + (size_t)r1 * 4096 + (size_t)(tau) * 64 + cb,                 \
      lds + (ldsmat) + buf_ * 16384 + 8192 + t * 16);                       \
} while (0)

#define LDA8(bufc, i) (*(const i32x4*)(lds + (bufc) * 16384                 \
    + (wm * 8 + (i)) * 1024 + laneoff))
#define LDB8(bufc, j) (*(const i32x4*)(lds + 32768 + (bufc) * 16384         \
    + (wn * 4 + (j)) * 1024 + laneoff))

#define MFMAQ(base, afr, bset) do {                                         \
  __builtin_amdgcn_s_setprio(1);                                            \
  _Pragma("unroll") for (int i_ = 0; i_ < 4; ++i_)                          \
  _Pragma("unroll") for (int j_ = 0; j_ < 4; ++j_)                          \
    acc[(base) + i_][j_] = __builtin_amdgcn_mfma_i32_16x16x64_i8(           \
        afr[i_], bfr[bset][j_], acc[(base) + i_][j_], 0, 0, 0);             \
  __builtin_amdgcn_s_setprio(0);                                            \
} while (0)

// vmN: 2 -> vmcnt(2), 0 -> vmcnt(0), else none.
#define KT8(t_, cur, nxt, s1, s2, r1x, r2x, vm1, vm2) do {                  \
  /* R1 */                                                                  \
  _Pragma("unroll") for (int i_ = 0; i_ < 4; ++i_) afhi[i_] = LDA8(cur, 4 + i_); \
  if (r1x) { _Pragma("unroll") for (int j_ = 0; j_ < 4; ++j_)               \
    bfr[nxt][j_] = LDB8(nxt, j_); }                                         \
  if (s1) STG(Brow, 32768, (t_) + 2);                                       \
  MFMAQ(0, aflo, cur);                                                      \
  if ((vm1) == 2) { WAITVM(2); } else if ((vm1) == 0) { WAITVM(0); }        \
  BAR;                                                                      \
  /* R2 */                                                                  \
  if (r2x) { _Pragma("unroll") for (int i_ = 0; i_ < 4; ++i_)               \
    aflo[i_] = LDA8(nxt, i_); }                                             \
  if (s2) STG(Arow, 0, (t_) + 2);                                           \
  MFMAQ(4, afhi, cur);                                                      \
  if ((vm2) == 2) { WAITVM(2); } else if ((vm2) == 0) { WAITVM(0); }        \
  BAR;                                                                      \
} while (0)

__global__ void __launch_bounds__(512, 2) gemm_i8_pipe(
    const signed char* __restrict__ A, const signed char* __restrict__ Bw,
    const float* __restrict__ sx, const float* __restrict__ scale_p,
    const float* __restrict__ bias, float* __restrict__ out) {
  __shared__ __align__(16) char lds[65536];

  const int t      = threadIdx.x;        // 0..511
  const int lane   = t & 63;
  const int wave   = t >> 6;
  const int wm     = wave >> 2;          // 0..1  (row half: 128 rows)
  const int wn     = wave & 3;           // 0..3  (col quarter: 64 cols)
  const int lane15 = lane & 15;
  const int lh     = lane >> 4;          // 0..3

  // round-3-verified zero-conflict swizzled read offset (XOR, not '+').
  const int laneoff = (lane15 * 64 + lh * 16) ^ ((lane15 & 8) << 2);

  // stage decode: LDS slot o = l*8192 + t*16 holds element a = o ^ (((o>>9)&1)<<5)
  const int ax = ((t >> 5) & 1) << 5;
  const int a0 = (t * 16) ^ ax;
  const int a1 = (8192 + t * 16) ^ ax;
  const int r0 = a0 >> 6;                // row 0..127
  const int r1 = a1 >> 6;                // row 128..255
  const int cb = a0 & 63;                // K-byte within 64B

  // XCD-aware swizzle: nwg = 512 (divisible by 8)
  const int bid   = blockIdx.x;
  const int wg    = (bid & 7) * 64 + (bid >> 3);
  const int ntile = wg & 15;             // 16 n-tiles
  const int mtile = wg >> 4;             // 32 m-tiles
  const int m0 = mtile * 256;
  const int n0 = ntile * 256;

  const char* Arow = (const char*)(A + (size_t)m0 * KDIM);
  const char* Brow = (const char*)(Bw + (size_t)n0 * KDIM);

  i32x4 acc[8][4] = {};
  i32x4 aflo[4], afhi[4], bfr[2][4];

  // Prologue: B(0),A(0),B(1),A(1); vmcnt(2) retires first 3 batches.
  STG(Brow, 32768, 0);
  STG(Arow, 0,     0);
  STG(Brow, 32768, 1);
  STG(Arow, 0,     1);
  WAITVM(2);
  BAR;
#pragma unroll
  for (int i_ = 0; i_ < 4; ++i_) aflo[i_] = LDA8(0, i_);
#pragma unroll
  for (int j_ = 0; j_ < 4; ++j_) bfr[0][j_] = LDB8(0, j_);

  // Main: 64 K-tiles; pairs keep buf index compile-time; t=0..61 full.
#pragma unroll 1
  for (int tp = 0; tp < 31; ++tp) {
    KT8(2 * tp,     0, 1, 1, 1, 1, 1, 2, 2);
    KT8(2 * tp + 1, 1, 0, 1, 1, 1, 1, 2, 2);
  }
  KT8(62, 0, 1, 0, 0, 1, 1, 0, -1);   // drain A(63) before R2 reads it
  KT8(63, 1, 0, 0, 0, 0, 0, -1, -1);

  // Epilogue: D layout col=lane&15, row=(lane>>4)*4+q (shape-determined,
  // dtype-independent — m89/m121-128). out = acc * sx[row]*sw + bias.
  const float sw = scale_p[0];
  float bv[4];
#pragma unroll
  for (int j = 0; j < 4; ++j) bv[j] = bias[n0 + wn * 64 + j * 16 + lane15];
#pragma unroll
  for (int i = 0; i < 8; ++i) {
    const int rowb = m0 + wm * 128 + i * 16 + lh * 4;
    float sxq[4];
#pragma unroll
    for (int q = 0; q < 4; ++q) sxq[q] = sx[rowb + q] * sw;
#pragma unroll
    for (int j = 0; j < 4; ++j) {
      const int col = n0 + wn * 64 + j * 16 + lane15;
#pragma unroll
      for (int q = 0; q < 4; ++q)
        out[(size_t)(rowb + q) * NDIM + col] = (float)acc[i][j][q] * sxq[q] + bv[j];
    }
  }
}

// ---------------- fallback: m97-style bf16 reg-staging (ws too small) ----------------
constexpr int FTILE = 128;
constexpr int FBK   = 64;

__global__ void __launch_bounds__(256) gemm_raw(
    const float* __restrict__ X, const int* __restrict__ W,
    const float* __restrict__ scale_p, const float* __restrict__ bias,
    float* __restrict__ out) {
  __shared__ short As[FTILE * FBK];
  __shared__ short Bs[FTILE * FBK];

  const int t      = threadIdx.x;
  const int lane   = t & 63;
  const int wave   = t >> 6;
  const int wm     = wave >> 1;
  const int wn     = wave & 1;
  const int lane15   = lane & 15;
  const int laneHalf = lane >> 4;

  const int bid   = blockIdx.x;
  const int wg    = (bid & 7) * 256 + (bid >> 3);
  const int ntile = wg & 31;
  const int mtile = wg >> 5;
  const int m0 = mtile * FTILE;
  const int n0 = ntile * FTILE;

  f32x4 acc[4][4] = {};

  for (int k0 = 0; k0 < KDIM; k0 += FBK) {
    __syncthreads();
#pragma unroll
    for (int r = 0; r < 8; ++r) {
      const int f   = r * 256 + t;
      const int row = f >> 4;
      const int c4  = (f & 15) * 4;
      f32x4 v = *(const f32x4*)(X + (size_t)(m0 + row) * KDIM + (k0 + c4));
      s16x4 h;
#pragma unroll
      for (int j = 0; j < 4; ++j) h[j] = f32_to_bf16_rn(v[j]);
      *(s16x4*)&As[row * FBK + c4] = h;

      i32x4 wv = *(const i32x4*)(W + (size_t)(n0 + row) * KDIM + (k0 + c4));
      s16x4 hw;
#pragma unroll
      for (int j = 0; j < 4; ++j) hw[j] = f32_to_bf16_rn((float)wv[j]);
      *(s16x4*)&Bs[row * FBK + c4] = hw;
    }
    __syncthreads();

#pragma unroll
    for (int kk = 0; kk < FBK; kk += 32) {
      const int kb = kk + laneHalf * 8;
      s16x8 af[4], bf[4];
#pragma unroll
      for (int i = 0; i < 4; ++i) {
        af[i] = *(const s16x8*)&As[(wm * 64 + i * 16 + lane15) * FBK + kb];
        bf[i] = *(const s16x8*)&Bs[(wn * 64 + i * 16 + lane15) * FBK + kb];
      }
#pragma unroll
      for (int i = 0; i < 4; ++i)
#pragma unroll
        for (int j = 0; j < 4; ++j)
          acc[i][j] = __builtin_amdgcn_mfma_f32_16x16x32_bf16(af[i], bf[j], acc[i][j], 0, 0, 0);
    }
  }

  const float s = scale_p[0];
#pragma unroll
  for (int j = 0; j < 4; ++j) {
    const int col = n0 + wn * 64 + j * 16 + lane15;
    const float bv = bias[col];
#pragma unroll
    for (int i = 0; i < 4; ++i) {
      const int row = m0 + wm * 64 + i * 16 + laneHalf * 4;
#pragma unroll
      for (int q = 0; q < 4; ++q)
        out[(size_t)(row + q) * NDIM + col] = acc[i][j][q] * s + bv;
    }
  }
}

extern "C" void kernel_launch(void* const* d_in, const int* in_sizes, int n_in,
                              void* d_out, int out_size, void* d_ws, size_t ws_size,
                              hipStream_t stream) {
  const float* x     = (const float*)d_in[0];
  const int*   w     = (const int*)d_in[1];    // integer inputs materialize as int32
  const float* scale = (const float*)d_in[2];
  const float* bias  = (const float*)d_in[3];
  float* out = (float*)d_out;

  const size_t a_bytes = (size_t)MDIM * KDIM;            // 33,554,432 (i8)
  const size_t b_bytes = (size_t)NDIM * KDIM;            // 16,777,216 (i8)
  const size_t need    = a_bytes + b_bytes + MDIM * 4;   // + sx floats

  if (ws_size >= need) {
    signed char* Ai8 = (signed char*)d_ws;
    signed char* Bi8 = Ai8 + a_bytes;
    float*       sxp = (float*)(Bi8 + b_bytes);
    quant_x_kernel<<<MDIM, 256, 0, stream>>>(x, Ai8, sxp);
    quant_w_kernel<<<4096, 256, 0, stream>>>(w, Bi8, (int)(b_bytes / 16));
    const int nwg = (MDIM / 256) * (NDIM / 256);  // 32*16 = 512
    gemm_i8_pipe<<<nwg, 512, 0, stream>>>(Ai8, Bi8, sxp, scale, bias, out);
  } else {
    const int nwg = (MDIM / FTILE) * (NDIM / FTILE);  // 2048
    gemm_raw<<<nwg, 256, 0, stream>>>(x, w, scale, bias, out);
  }
}